// Round 1
// baseline (211.046 us; speedup 1.0000x reference)
//
#include <hip/hip_runtime.h>

namespace {

struct LP { int o11, o21, o12, o22; float w11, w21, w12, w22; };

__device__ inline LP make_lp(float hx, float wy, float inv, int H) {
    float x = hx * inv;
    float y = wy * inv;
    float x1 = floorf(x), x2 = ceilf(x);
    float y1 = floorf(y), y2 = ceilf(y);
    int xi1 = min(max((int)x1, 0), H - 1);
    int xi2 = min(max((int)x2, 0), H - 1);
    int yi1 = min(max((int)y1, 0), H - 1);
    int yi2 = min(max((int)y2, 0), H - 1);
    LP p;
    p.o11 = xi1 * H + yi1;
    p.o21 = xi2 * H + yi1;
    p.o12 = xi1 * H + yi2;
    p.o22 = xi2 * H + yi2;
    p.w11 = (x2 - x) * (y2 - y);
    p.w21 = (x - x1) * (y2 - y);
    p.w12 = (x2 - x) * (y - y1);
    p.w22 = (x - x1) * (y - y1);
    return p;
}

__device__ inline float sample(const float* __restrict__ f, const LP& p, int C, int c) {
    return p.w11 * f[p.o11 * C + c] + p.w21 * f[p.o21 * C + c]
         + p.w12 * f[p.o12 * C + c] + p.w22 * f[p.o22 * C + c];
}

} // namespace

__global__ __launch_bounds__(256) void GraphProjection_57483842289710_kernel(
    const float* __restrict__ coord,
    const float* __restrict__ f56,
    const float* __restrict__ f28,
    const float* __restrict__ f14,
    const float* __restrict__ f7,
    float* __restrict__ out,
    int n)
{
    int i = blockIdx.x;
    if (i >= n) return;

    float X = coord[i * 3 + 0];
    float Y = coord[i * 3 + 1];
    float Z = coord[i * 3 + 2];

    // h = 250*(-Y)/(-Z) + 112 ; w = 250*X/(-Z) + 112  (same op order as ref)
    float h = 250.0f * (-Y) / (-Z) + 112.0f;
    float w = 250.0f * X / (-Z) + 112.0f;
    h = fminf(fmaxf(h, 0.0f), 223.0f);
    w = fminf(fmaxf(w, 0.0f), 223.0f);

    // Per-level bilinear params, kept in named scalars (no runtime-indexed
    // arrays -> stays in registers, no scratch).
    LP p0 = make_lp(h, w, 0.25f,    56);
    LP p1 = make_lp(h, w, 0.125f,   28);
    LP p2 = make_lp(h, w, 0.0625f,  14);
    LP p3 = make_lp(h, w, 0.03125f,  7);

    float* __restrict__ orow = out + (size_t)i * 963;

    #pragma unroll
    for (int it = 0; it < 4; ++it) {
        int j = threadIdx.x + it * 256;
        if (j < 963) {
            float v;
            int ch = j - 3;
            if (j < 3)         v = coord[i * 3 + j];
            else if (ch < 64)  v = sample(f56, p0, 64,  ch);
            else if (ch < 192) v = sample(f28, p1, 128, ch - 64);
            else if (ch < 448) v = sample(f14, p2, 256, ch - 192);
            else               v = sample(f7,  p3, 512, ch - 448);
            orow[j] = v;
        }
    }
}

extern "C" void kernel_launch(void* const* d_in, const int* in_sizes, int n_in,
                              void* d_out, int out_size, void* d_ws, size_t ws_size,
                              hipStream_t stream) {
    const float* coord = (const float*)d_in[0];
    const float* f56   = (const float*)d_in[1];
    const float* f28   = (const float*)d_in[2];
    const float* f14   = (const float*)d_in[3];
    const float* f7    = (const float*)d_in[4];
    float* out = (float*)d_out;

    int n = in_sizes[0] / 3;  // 131072 points
    GraphProjection_57483842289710_kernel<<<n, 256, 0, stream>>>(
        coord, f56, f28, f14, f7, out, n);
}

// Round 2
// 167.222 us; speedup vs baseline: 1.2621x; 1.2621x over previous
//
#include <hip/hip_runtime.h>

// 4-byte-aligned float quad: output rows are 963 floats (12 mod 16 bytes), so
// per-thread 16B stores land on 4B-aligned addresses. gfx950 handles
// dword-aligned dwordx4 global stores; worst case the compiler splits into
// dword stores, which is no worse than scalar.
struct F4 { float x, y, z, w; };

__global__ __launch_bounds__(256) void GraphProjection_57483842289710_kernel(
    const float* __restrict__ coord,
    const float* __restrict__ f56,
    const float* __restrict__ f28,
    const float* __restrict__ f14,
    const float* __restrict__ f7,
    float* __restrict__ out,
    int n)
{
    const int i = blockIdx.x;
    const int t = threadIdx.x;

    float* __restrict__ orow = out + (size_t)i * 963;

    // Lanes 240..242 of the last wave write the coord triple; 243..255 idle.
    if (t >= 240) {
        if (t < 243) orow[t - 240] = coord[i * 3 + (t - 240)];
        return;
    }

    // Per-thread h,w (redundant across the block but only ~20 VALU ops incl.
    // the two divides; hides under the memory stream).
    float X = coord[i * 3 + 0];
    float Y = coord[i * 3 + 1];
    float Z = coord[i * 3 + 2];
    float h = 250.0f * (-Y) / (-Z) + 112.0f;   // same op order as reference
    float w = 250.0f * X / (-Z) + 112.0f;
    h = fminf(fmaxf(h, 0.0f), 223.0f);
    w = fminf(fmaxf(w, 0.0f), 223.0f);

    // Thread t owns channels ch..ch+3. Level boundaries (64,192,448) are
    // multiples of 4, so a quad never straddles levels -> exactly ONE
    // bilinear setup per thread.
    const int ch = 4 * t;
    const float* f; int C, H; float inv; int c;
    if (ch < 64)       { f = f56; C = 64;  H = 56; inv = 0.25f;    c = ch;       }
    else if (ch < 192) { f = f28; C = 128; H = 28; inv = 0.125f;   c = ch - 64;  }
    else if (ch < 448) { f = f14; C = 256; H = 14; inv = 0.0625f;  c = ch - 192; }
    else               { f = f7;  C = 512; H = 7;  inv = 0.03125f; c = ch - 448; }

    float x = h * inv, y = w * inv;
    float x1 = floorf(x), x2 = ceilf(x);
    float y1 = floorf(y), y2 = ceilf(y);
    int xi1 = min(max((int)x1, 0), H - 1);
    int xi2 = min(max((int)x2, 0), H - 1);
    int yi1 = min(max((int)y1, 0), H - 1);
    int yi2 = min(max((int)y2, 0), H - 1);
    float w11 = (x2 - x) * (y2 - y);
    float w21 = (x - x1) * (y2 - y);
    float w12 = (x2 - x) * (y - y1);
    float w22 = (x - x1) * (y - y1);

    // Texel bases: (xi*H+yi)*C is a multiple of 64 floats -> 256B aligned;
    // +c (multiple of 4 floats) keeps 16B alignment -> aligned float4 loads.
    const float4 a = *reinterpret_cast<const float4*>(f + (xi1 * H + yi1) * C + c);
    const float4 b = *reinterpret_cast<const float4*>(f + (xi2 * H + yi1) * C + c);
    const float4 d = *reinterpret_cast<const float4*>(f + (xi1 * H + yi2) * C + c);
    const float4 e = *reinterpret_cast<const float4*>(f + (xi2 * H + yi2) * C + c);

    F4 r;
    r.x = w11 * a.x + w21 * b.x + w12 * d.x + w22 * e.x;
    r.y = w11 * a.y + w21 * b.y + w12 * d.y + w22 * e.y;
    r.z = w11 * a.z + w21 * b.z + w12 * d.z + w22 * e.z;
    r.w = w11 * a.w + w21 * b.w + w12 * d.w + w22 * e.w;

    *reinterpret_cast<F4*>(orow + 3 + ch) = r;
}

extern "C" void kernel_launch(void* const* d_in, const int* in_sizes, int n_in,
                              void* d_out, int out_size, void* d_ws, size_t ws_size,
                              hipStream_t stream) {
    const float* coord = (const float*)d_in[0];
    const float* f56   = (const float*)d_in[1];
    const float* f28   = (const float*)d_in[2];
    const float* f14   = (const float*)d_in[3];
    const float* f7    = (const float*)d_in[4];
    float* out = (float*)d_out;

    int n = in_sizes[0] / 3;  // 131072 points
    GraphProjection_57483842289710_kernel<<<n, 256, 0, stream>>>(
        coord, f56, f28, f14, f7, out, n);
}